// Round 3
// baseline (84.609 us; speedup 1.0000x reference)
//
#include <hip/hip_runtime.h>
#include <math.h>

#define BB 8
#define NN 256
#define XHIN 9
#define XHHID 64
#define POSHID 192

// ---------------------------------------------------------------------------
// Single fused kernel: one block per (b,i) row, 2048 blocks total.
//   phase 0: in-block masked mean of x over all 256 nodes (redundant per
//            block, but ~100 cycles — cheaper than a separate kernel launch
//            + global round-trip through workspace)
//   phase 1: centered x -> LDS, distances d_ij for all j
//   phase 2: S_i[f] = sum_j mask_j * sin(2*pi*d_ij*freq_f)  (cos in [64,128))
//            HW v_sin/v_cos on revolutions after v_fract range reduction
//   phase 3a (threads 0..191):   out[..,64:256] = mi*(S_i@W_pos)/cnt
//                                               + mi*256/cnt * b_pos
//   phase 3b (threads 192..255): out[..,0:64]  = ([xc_i,h_i]@W_xh + b_xh)*mi
// Sum-then-matmul reassociation removes the (B,N,N,128)@(128,192) matmul.
// ---------------------------------------------------------------------------
__global__ __launch_bounds__(256) void fused_kernel(
    const float* __restrict__ xh, const float* __restrict__ mask,
    const float* __restrict__ Wxh, const float* __restrict__ bxh,
    const float* __restrict__ Wp, const float* __restrict__ bp,
    float* __restrict__ out)
{
  const int blk = blockIdx.x;
  const int b = blk >> 8;
  const int i = blk & 255;
  const int tid = threadIdx.x;

  __shared__ __align__(16) float4 xc_s[NN];      // centered x, mask in .w
  __shared__ float2 dm_s[NN];                    // (dist_ij, mask_j)
  __shared__ float part[4][128];
  __shared__ __align__(16) float Ssc[128];
  __shared__ float red[4][4];

  // phase 0: load this node's x + mask, block-reduce masked sums
  const int j = tid;
  const float* p = xh + (b * NN + j) * XHIN;
  const float x0 = p[0], x1 = p[1], x2 = p[2];
  const float m = mask[b * NN + j];

  float a0 = x0 * m, a1 = x1 * m, a2 = x2 * m, a3 = m;
  #pragma unroll
  for (int off = 32; off > 0; off >>= 1) {
    a0 += __shfl_down(a0, off, 64);
    a1 += __shfl_down(a1, off, 64);
    a2 += __shfl_down(a2, off, 64);
    a3 += __shfl_down(a3, off, 64);
  }
  const int lane = tid & 63, wv = tid >> 6;
  if (lane == 0) { red[wv][0] = a0; red[wv][1] = a1; red[wv][2] = a2; red[wv][3] = a3; }
  __syncthreads();
  const float s0 = red[0][0] + red[1][0] + red[2][0] + red[3][0];
  const float s1 = red[0][1] + red[1][1] + red[2][1] + red[3][1];
  const float s2 = red[0][2] + red[1][2] + red[2][2] + red[3][2];
  const float cnt = red[0][3] + red[1][3] + red[2][3] + red[3][3];
  const float inv = 1.0f / cnt;

  // phase 1: center, stage to LDS, compute distances
  const float xc0 = (x0 - s0 * inv) * m;
  const float xc1 = (x1 - s1 * inv) * m;
  const float xc2 = (x2 - s2 * inv) * m;
  xc_s[j] = make_float4(xc0, xc1, xc2, m);
  __syncthreads();

  const float4 xi = xc_s[i];                     // b128 broadcast
  {
    const float dx = xi.x - xc0;
    const float dy = xi.y - xc1;
    const float dz = xi.z - xc2;
    const float sq = fmaf(dx, dx, fmaf(dy, dy, dz * dz));
    dm_s[j] = make_float2(sqrtf(sq + 1e-12f), m);
  }
  __syncthreads();

  // phase 2: thread (jg,f): accumulate sin/cos for freq f over 64 j's
  const int f = tid & 63, jg = tid >> 6;
  // freq = 100^(f/64) = exp2(f * log2(100)/64)
  const float freq = __builtin_exp2f((float)f * 0.10381025296523007f);
  float ss = 0.f, cc = 0.f;
  const float2* dmp = dm_s + jg * 64;
  #pragma unroll 16
  for (int u = 0; u < 64; ++u) {
    const float2 dm = dmp[u];                    // one b64 broadcast / iter
    const float rv = __builtin_amdgcn_fractf(dm.x * freq);  // revolutions
    ss = fmaf(__builtin_amdgcn_sinf(rv), dm.y, ss);
    cc = fmaf(__builtin_amdgcn_cosf(rv), dm.y, cc);
  }
  part[jg][f] = ss;
  part[jg][64 + f] = cc;
  __syncthreads();

  const float mi = xi.w;
  if (tid < 128)
    Ssc[tid] = (part[0][tid] + part[1][tid] + part[2][tid] + part[3][tid]) * (mi / cnt);
  __syncthreads();

  if (tid < POSHID) {
    // phase 3a: 192 pe outputs, 128-MAC dot; Ssc via b128 broadcasts
    const float4* S4 = (const float4*)Ssc;
    float acc = bp[tid] * (mi * 256.0f / cnt);
    #pragma unroll 8
    for (int k4 = 0; k4 < 32; ++k4) {
      const float4 s = S4[k4];
      const float* w = Wp + (k4 * 4) * POSHID + tid;
      acc = fmaf(s.x, w[0 * POSHID], acc);
      acc = fmaf(s.y, w[1 * POSHID], acc);
      acc = fmaf(s.z, w[2 * POSHID], acc);
      acc = fmaf(s.w, w[3 * POSHID], acc);
    }
    out[(size_t)(b * NN + i) * 256 + 64 + tid] = acc;
  } else {
    // phase 3b (concurrent): 64 xh-embedding outputs for node i
    const int oo = tid - POSHID;                 // 0..63
    const float* hi = xh + (b * NN + i) * XHIN;  // same addr all lanes: L1 broadcast
    float acc = bxh[oo];
    acc = fmaf(xi.x, Wxh[0 * XHHID + oo], acc);
    acc = fmaf(xi.y, Wxh[1 * XHHID + oo], acc);
    acc = fmaf(xi.z, Wxh[2 * XHHID + oo], acc);
    #pragma unroll
    for (int k = 3; k < XHIN; ++k)
      acc = fmaf(hi[k], Wxh[k * XHHID + oo], acc);
    out[(size_t)(b * NN + i) * 256 + oo] = acc * mi;
  }
}

extern "C" void kernel_launch(void* const* d_in, const int* in_sizes, int n_in,
                              void* d_out, int out_size, void* d_ws, size_t ws_size,
                              hipStream_t stream) {
  // setup_inputs order: t, xh, node_mask, edge_mask, W_xh, b_xh, W_pos, b_pos
  const float* xh   = (const float*)d_in[1];
  const float* mask = (const float*)d_in[2];
  const float* Wxh  = (const float*)d_in[4];
  const float* bxh  = (const float*)d_in[5];
  const float* Wp   = (const float*)d_in[6];
  const float* bp   = (const float*)d_in[7];
  float* out = (float*)d_out;

  fused_kernel<<<BB * NN, 256, 0, stream>>>(xh, mask, Wxh, bxh, Wp, bp, out);
}